// Round 1
// baseline (1026.962 us; speedup 1.0000x reference)
//
#include <hip/hip_runtime.h>
#include <hip/hip_bf16.h>
#include <math.h>

// ---------------------------------------------------------------------------
// SimpleBetterGCN: h1 = relu(A @ (x@W1+b1)); h2 = relu(A @ (h1@W2+b2));
// h = h1+h2; w = softmax(h@att_w+att_b over nodes); g = sum(w*h); out = g@Wc+bc
// ---------------------------------------------------------------------------

#define HID 128

__device__ __forceinline__ float relu(float v) { return v > 0.f ? v : 0.f; }

// --------------------------- GEMM: [N,K] @ [K,128] -------------------------
// Whole weight matrix in LDS. 64-row x 128-col tile per 256-thread block.
// Thread register tile: 8 rows x 4 cols.
template <int K, bool RELU_IN>
__global__ __launch_bounds__(256) void gemm_kernel(
    const float* __restrict__ in, const float* __restrict__ w,
    const float* __restrict__ bias, float* __restrict__ out, int Nrows) {
  __shared__ float w_lds[K * HID];
  __shared__ float in_lds[64 * K];
  const int t = threadIdx.x;
  const int R0 = blockIdx.x * 64;

  // Stage weights (flat contiguous copy)
  for (int idx = t * 4; idx < K * HID; idx += 1024) {
    *(float4*)&w_lds[idx] = *(const float4*)&w[idx];
  }
  // Stage input tile (tile is a contiguous 64*K chunk of row-major input)
  const int limit = Nrows * K;
  for (int idx = t * 4; idx < 64 * K; idx += 1024) {
    int g = R0 * K + idx;
    float4 v;
    if (g < limit) {
      v = *(const float4*)&in[g];
    } else {
      v.x = v.y = v.z = v.w = 0.f;
    }
    if (RELU_IN) {
      v.x = relu(v.x); v.y = relu(v.y); v.z = relu(v.z); v.w = relu(v.w);
    }
    *(float4*)&in_lds[idx] = v;
  }
  __syncthreads();

  const int i = t >> 5;        // 0..7  -> row group
  const int j = t & 31;        // 0..31 -> col group
  const int r0 = i * 8;
  const int c0 = j * 4;
  float4 bv = *(const float4*)&bias[c0];
  float acc[8][4] = {};

#pragma unroll 4
  for (int k = 0; k < K; ++k) {
    float4 wv = *(const float4*)&w_lds[k * HID + c0];
#pragma unroll
    for (int ii = 0; ii < 8; ++ii) {
      float a = in_lds[(r0 + ii) * K + k];
      acc[ii][0] = fmaf(a, wv.x, acc[ii][0]);
      acc[ii][1] = fmaf(a, wv.y, acc[ii][1]);
      acc[ii][2] = fmaf(a, wv.z, acc[ii][2]);
      acc[ii][3] = fmaf(a, wv.w, acc[ii][3]);
    }
  }

#pragma unroll
  for (int ii = 0; ii < 8; ++ii) {
    int gr = R0 + r0 + ii;
    if (gr < Nrows) {
      float4 o;
      o.x = acc[ii][0] + bv.x;
      o.y = acc[ii][1] + bv.y;
      o.z = acc[ii][2] + bv.z;
      o.w = acc[ii][3] + bv.w;
      *(float4*)&out[(size_t)gr * HID + c0] = o;
    }
  }
}

// --------------------------- SPMM (COO, rows sorted) -----------------------
// out[r,:] += v * mat[c,:].  Per-wave contiguous edge segment; float2/lane
// covers 128 dims; register accumulation, atomic flush on row change.
__global__ __launch_bounds__(256) void spmm_kernel(
    const float* __restrict__ mat, const int* __restrict__ rows,
    const int* __restrict__ cols, const float* __restrict__ vals,
    float* __restrict__ out, int E) {
  const int gw = (blockIdx.x * blockDim.x + threadIdx.x) >> 6;
  const int lane = threadIdx.x & 63;
  const int nw = (gridDim.x * blockDim.x) >> 6;
  const int S = (E + nw - 1) / nw;
  int start = gw * S;
  int end = start + S;
  if (end > E) end = E;
  if (start >= end) return;

  const int d = lane * 2;
  float2 acc = {0.f, 0.f};
  int curRow = rows[start];

  for (int e = start; e < end; ++e) {
    int c = cols[e];
    float v = vals[e];
    float2 m = *(const float2*)(mat + c * HID + d);
    acc.x = fmaf(v, m.x, acc.x);
    acc.y = fmaf(v, m.y, acc.y);
    int nr = (e + 1 < end) ? rows[e + 1] : -1;
    if (nr != curRow) {
      atomicAdd(out + (size_t)curRow * HID + d, acc.x);
      atomicAdd(out + (size_t)curRow * HID + d + 1, acc.y);
      acc.x = 0.f;
      acc.y = 0.f;
      curRow = nr;
    }
  }
}

// --------------------------- attention: per-node scores --------------------
// s[n] = dot(relu(h1[n]) + relu(h2[n]), att_w) + att_b.  One wave per node.
__global__ __launch_bounds__(256) void att_score_kernel(
    const float* __restrict__ h1, const float* __restrict__ h2,
    const float* __restrict__ attw, const float* __restrict__ attb,
    float* __restrict__ s, int N) {
  const int gw = (blockIdx.x * blockDim.x + threadIdx.x) >> 6;
  const int lane = threadIdx.x & 63;
  const int nw = (gridDim.x * blockDim.x) >> 6;
  const float2 w = *(const float2*)(attw + lane * 2);
  const float b = attb[0];

  for (int n = gw; n < N; n += nw) {
    float2 a = *(const float2*)(h1 + (size_t)n * HID + lane * 2);
    float2 c = *(const float2*)(h2 + (size_t)n * HID + lane * 2);
    float hx = relu(a.x) + relu(c.x);
    float hy = relu(a.y) + relu(c.y);
    float p = hx * w.x + hy * w.y;
#pragma unroll
    for (int off = 1; off < 64; off <<= 1) p += __shfl_xor(p, off);
    if (lane == 0) s[n] = p + b;
  }
}

// --------------------------- max over s + zero accumulators -----------------
// Single block.  small[0] = max(s); small[1] = den = 0; small[2..129] = num = 0
__global__ __launch_bounds__(1024) void att_max_kernel(
    const float* __restrict__ s, float* __restrict__ small, int N) {
  __shared__ float red[1024];
  const int t = threadIdx.x;
  float m = -INFINITY;
  for (int i = t; i < N; i += 1024) m = fmaxf(m, s[i]);
  red[t] = m;
  __syncthreads();
  for (int off = 512; off > 0; off >>= 1) {
    if (t < off) red[t] = fmaxf(red[t], red[t + off]);
    __syncthreads();
  }
  if (t == 0) small[0] = red[0];
  if (t >= 1 && t < 130) small[t] = 0.f;
}

// --------------------------- weighted sums ---------------------------------
// den = sum exp(s-m); num[d] = sum exp(s-m) * h[n][d].  One wave per node,
// grid-stride; per-wave register accumulation; atomics once per wave.
__global__ __launch_bounds__(256) void att_wsum_kernel(
    const float* __restrict__ h1, const float* __restrict__ h2,
    const float* __restrict__ s, float* __restrict__ small, int N) {
  const int gw = (blockIdx.x * blockDim.x + threadIdx.x) >> 6;
  const int lane = threadIdx.x & 63;
  const int nw = (gridDim.x * blockDim.x) >> 6;
  const float m = small[0];

  float2 accn = {0.f, 0.f};
  float accd = 0.f;
  for (int n = gw; n < N; n += nw) {
    float2 a = *(const float2*)(h1 + (size_t)n * HID + lane * 2);
    float2 c = *(const float2*)(h2 + (size_t)n * HID + lane * 2);
    float hx = relu(a.x) + relu(c.x);
    float hy = relu(a.y) + relu(c.y);
    float e = expf(s[n] - m);
    accn.x = fmaf(e, hx, accn.x);
    accn.y = fmaf(e, hy, accn.y);
    accd += e;
  }
  atomicAdd(&small[2 + lane * 2], accn.x);
  atomicAdd(&small[2 + lane * 2 + 1], accn.y);
  if (lane == 0) atomicAdd(&small[1], accd);
}

// --------------------------- final: g = num/den; out = g @ cls_w + cls_b ----
__global__ __launch_bounds__(128) void att_final_kernel(
    const float* __restrict__ small, const float* __restrict__ clsw,
    const float* __restrict__ clsb, float* __restrict__ out) {
  __shared__ float g[HID];
  const int t = threadIdx.x;
  const float den = small[1];
  g[t] = small[2 + t] / den;
  __syncthreads();
  if (t < 10) {
    float acc = clsb[t];
    for (int d = 0; d < HID; ++d) acc = fmaf(g[d], clsw[d * 10 + t], acc);
    out[t] = acc;
  }
}

extern "C" void kernel_launch(void* const* d_in, const int* in_sizes, int n_in,
                              void* d_out, int out_size, void* d_ws,
                              size_t ws_size, hipStream_t stream) {
  const float* x = (const float*)d_in[0];
  const int* erows = (const int*)d_in[1];
  const int* ecols = (const int*)d_in[2];
  const float* evals = (const float*)d_in[3];
  const float* fc1w = (const float*)d_in[4];
  const float* fc1b = (const float*)d_in[5];
  const float* fc2w = (const float*)d_in[6];
  const float* fc2b = (const float*)d_in[7];
  const float* attw = (const float*)d_in[8];
  const float* attb = (const float*)d_in[9];
  const float* clsw = (const float*)d_in[10];
  const float* clsb = (const float*)d_in[11];
  float* out = (float*)d_out;

  const int N = in_sizes[0] / 64;   // 100000
  const int E = in_sizes[1];        // 3200000

  float* ws = (float*)d_ws;
  float* t = ws;                               // [N,128] t1 then t2
  float* h1 = ws + (size_t)N * HID;            // [N,128] pre-relu accum
  float* h2 = ws + (size_t)2 * N * HID;        // [N,128] pre-relu accum
  float* s = ws + (size_t)3 * N * HID;         // [N]
  float* small = s + N;                        // [130]: m, den, num[128]

  // Zero both spmm accumulators (contiguous region)
  hipMemsetAsync(h1, 0, (size_t)2 * N * HID * sizeof(float), stream);

  // t1 = x @ fc1_w + fc1_b
  gemm_kernel<64, false><<<(N + 63) / 64, 256, 0, stream>>>(x, fc1w, fc1b, t, N);
  // h1acc = A @ t1
  spmm_kernel<<<2048, 256, 0, stream>>>(t, erows, ecols, evals, h1, E);
  // t2 = relu(h1acc) @ fc2_w + fc2_b
  gemm_kernel<128, true><<<(N + 63) / 64, 256, 0, stream>>>(h1, fc2w, fc2b, t, N);
  // h2acc = A @ t2
  spmm_kernel<<<2048, 256, 0, stream>>>(t, erows, ecols, evals, h2, E);
  // scores
  att_score_kernel<<<2048, 256, 0, stream>>>(h1, h2, attw, attb, s, N);
  // max + zero num/den
  att_max_kernel<<<1, 1024, 0, stream>>>(s, small, N);
  // weighted sums
  att_wsum_kernel<<<512, 256, 0, stream>>>(h1, h2, s, small, N);
  // final 10-class output
  att_final_kernel<<<1, 128, 0, stream>>>(small, clsw, clsb, out);
}